// Round 1
// baseline (244.434 us; speedup 1.0000x reference)
//
#include <hip/hip_runtime.h>

// features: (B=4, C=1024, 14, 14) fp32; H_Box/O_Box: (4,16,6); im_h=480, im_w=640
// Outputs (flat concat, fp32):
//   H_Node   (4,16,1024,7,7)      = 3,211,264   @ 0
//   O_Node   (4,16,1024,7,7)      = 3,211,264   @ 3,211,264
//   H_O_Node (4,16,16,1024,7,7)   = 51,380,224  @ 6,422,528
//   geometry (4,16,16,9)          = 9,216       @ 57,802,752
//   h_ratio  (4,16)               = 64          @ 57,811,968
//   o_ratio  (4,16)               = 64          @ 57,812,032
//   ho_ratio (4,16,16)            = 1,024       @ 57,812,096

#define C_CH   1024
#define HW     14
#define PLANE  196              // 14*14 floats per channel plane
#define OUTS   7
#define TILE   (C_CH * OUTS * OUTS)   // 50176 elems per roi
#define OFF_O  3211264
#define OFF_U  6422528
#define OFF_G  57802752
#define OFF_HR 57811968
#define OFF_OR 57812032
#define OFF_UR 57812096

#define CH_PER_BLK   32         // channels staged per block
#define ROI_PER_BLK  16         // rois sharing one staging (288 % 16 == 0 -> same b)
#define CH_PER_WAVE  8          // 4 waves x 8 = 32

#define SCR    (CH_PER_BLK * PLANE)      // 6272 dwords: per-wave output scratch base
#define WSCR   (CH_PER_WAVE * 49)        // 392 dwords scratch per wave
#define BXS    (SCR + 4 * WSCR)          // 7840 dwords: staged box slice base

// grid = (32 channel-groups, 72 roi-groups), block = 256.
// Stage 32 planes -> LDS (coalesced float4). Lane = output position (49 of 64);
// wave owns 8 channels; block loops 16 rois over the staged planes.
// NEW vs prior version: per-wave results are bounced through an LDS scratch in
// output order and stored as float4 (2x global_store_dwordx4 of 784 B per
// wave-roi instead of 8x 196-B scalar-dword stores) -> 4x fewer store instrs,
// 4x wider. Boxes staged to LDS once per block (kills per-roi s_load latency).
__global__ __launch_bounds__(256) void roi_align_kernel(
    const float* __restrict__ feat,
    const float* __restrict__ HBox,
    const float* __restrict__ OBox,
    const int* __restrict__ im_h_p,
    const int* __restrict__ im_w_p,
    float* __restrict__ out)
{
    __shared__ float lds[BXS + 192];     // 8032 floats = 32128 B (5 blocks/CU)

    const int c0 = blockIdx.x * CH_PER_BLK;
    const int g0 = blockIdx.y * ROI_PER_BLK;
    const int b  = g0 / 288;                    // block-uniform

    // ---- stage 32 contiguous planes, fully coalesced ----
    {
        const float4* g4 = (const float4*)(feat + ((size_t)b * C_CH + c0) * PLANE);
        float4* l4 = (float4*)lds;
        for (int i = threadIdx.x; i < (CH_PER_BLK * PLANE / 4); i += 256)
            l4[i] = g4[i];
    }
    // ---- stage this batch's box slices (16x6 H + 16x6 O = 192 floats) ----
    if (threadIdx.x < 96)
        lds[BXS + threadIdx.x] = HBox[b * 96 + threadIdx.x];
    else if (threadIdx.x < 192)
        lds[BXS + threadIdx.x] = OBox[b * 96 + (threadIdx.x - 96)];
    __syncthreads();

    const int lane = threadIdx.x & 63;
    const int wave = threadIdx.x >> 6;
    if (lane >= 49) return;                     // no further block-wide syncs

    const int pos = lane;
    const int oy = pos / 7;
    const int ox = pos - oy * 7;

    const float im_w = (float)(*im_w_p);
    const float im_h = (float)(*im_h_p);
    const float scx = (224.0f / im_w) * (1.0f / 16.0f);
    const float scy = (224.0f / im_h) * (1.0f / 16.0f);

    const float* ldw = lds + (wave * CH_PER_WAVE) * PLANE;
    const int cw = c0 + wave * CH_PER_WAVE;     // first channel this wave owns

    float* sw = lds + SCR + wave * WSCR;        // wave-private scratch (392 f)
    const float4* sv = (const float4*)sw;       // 98 float4, output order
    const float* hbx = lds + BXS;               // staged H boxes (16x6)
    const float* obx = lds + BXS + 96;          // staged O boxes (16x6)

    for (int ri = 0; ri < ROI_PER_BLK; ++ri) {
        const int g = g0 + ri;
        const int j = g - b * 288;              // block-uniform branch below

        float x1, y1, x2, y2;
        size_t outBase;
        if (j < 16) {
            const float* bx = hbx + j * 6;
            x1 = bx[0]; y1 = bx[1]; x2 = bx[2]; y2 = bx[3];
            outBase = (size_t)(b * 16 + j) * TILE;
        } else if (j < 32) {
            const float* bx = obx + (j - 16) * 6;
            x1 = bx[0]; y1 = bx[1]; x2 = bx[2]; y2 = bx[3];
            outBase = OFF_O + (size_t)(b * 16 + (j - 16)) * TILE;
        } else {
            const int u = j - 32;
            const float* hb = hbx + (u >> 4) * 6;
            const float* ob = obx + (u & 15) * 6;
            x1 = fminf(ob[0], hb[0]);
            y1 = fminf(ob[1], hb[1]);
            x2 = fmaxf(ob[2], hb[2]);
            y2 = fmaxf(ob[3], hb[3]);
            outBase = OFF_U + (size_t)(b * 256 + u) * TILE;
        }

        // bilinear descriptor (once per roi, loop-invariant registers)
        const float bx1 = x1 * scx;
        const float by1 = y1 * scy;
        const float bw = (x2 * scx - bx1) * (1.0f / OUTS);
        const float bh = (y2 * scy - by1) * (1.0f / OUTS);
        float X = bx1 + ((float)ox + 0.5f) * bw;
        float Y = by1 + ((float)oy + 0.5f) * bh;
        X = fminf(fmaxf(X, 0.0f), (float)(HW - 1));
        Y = fminf(fmaxf(Y, 0.0f), (float)(HW - 1));
        // clamp base to <=12 so x1i=x0+1 always; X==13 -> lx=1 -> weight flows
        // to f01 which equals reference's clamped f00. Bit-equivalent result.
        const int x0 = min((int)floorf(X), HW - 2);
        const int y0 = min((int)floorf(Y), HW - 2);
        const float lx = X - (float)x0;
        const float ly = Y - (float)y0;
        const float w00 = (1.0f - ly) * (1.0f - lx);
        const float w01 = (1.0f - ly) * lx;
        const float w10 = ly * (1.0f - lx);
        const float w11 = ly * lx;
        const int off = y0 * HW + x0;

        const float* lp = ldw + off;
#pragma unroll
        for (int k = 0; k < CH_PER_WAVE; ++k) {
            // dword offsets {0,1,14,15} from per-channel base -> 2x ds_read2_b32
            const float f00 = lp[0];
            const float f01 = lp[1];
            const float f10 = lp[HW];
            const float f11 = lp[HW + 1];
            // scratch in exact output order: [ch][pos]; stride-1 dword writes
            // across 49 lanes -> <=2-way bank aliasing (free)
            sw[k * 49 + pos] = f00 * w00 + f01 * w01 + f10 * w10 + f11 * w11;
            lp += PLANE;
        }

        // Fence the COMPILER from hoisting the cross-lane readback above the
        // ds_writes (per-thread alias analysis can't see the lane exchange).
        // HW-side, LDS ops complete in order per wave, so this is sufficient.
        asm volatile("s_waitcnt lgkmcnt(0)" ::: "memory");

        // readback in output order and store wide: 2x 784-B dwordx4 stores
        // (was 8x 196-B scalar stores). Base is 16-B aligned: cw%8==0.
        float4* og = (float4*)(out + outBase + (size_t)cw * 49);
        const float4 a = sv[pos];
        const float4 c = sv[pos + 49];
        og[pos] = a;
        og[pos + 49] = c;
    }
}

// Pairwise geometry + ratios. 1024 threads total (4 blocks x 256).
__global__ __launch_bounds__(256) void geom_kernel(
    const float* __restrict__ HBox,
    const float* __restrict__ OBox,
    const int* __restrict__ im_h_p,
    const int* __restrict__ im_w_p,
    float* __restrict__ geo,
    float* __restrict__ h_ratio,
    float* __restrict__ o_ratio,
    float* __restrict__ ho_ratio)
{
    const int p = blockIdx.x * 256 + threadIdx.x;   // 0..1023
    if (p >= 1024) return;
    const float im_w = (float)(*im_w_p);
    const float im_h = (float)(*im_h_p);
    const float im_area = im_h * im_w;

    const int b = p >> 8;
    const int h = (p >> 4) & 15;
    const int o = p & 15;
    const float* hb = HBox + (b * 16 + h) * 6;
    const float* ob = OBox + (b * 16 + o) * 6;
    const float hx1 = hb[0], hy1 = hb[1], hx2 = hb[2], hy2 = hb[3];
    const float ox1 = ob[0], oy1 = ob[1], ox2 = ob[2], oy2 = ob[3];

    const float h_cx = (hx1 + hx2) * 0.5f, h_cy = (hy1 + hy2) * 0.5f;
    const float h_w = hx2 - hx1, h_h = hy2 - hy1;
    const float o_cx = (ox1 + ox2) * 0.5f, o_cy = (oy1 + oy2) * 0.5f;
    const float o_w = ox2 - ox1, o_h = oy2 - oy1;

    const float dxc = h_cx - o_cx;
    const float dyc = h_cy - o_cy;
    const float adx = fabsf(dxc), ady = fabsf(dyc);

    const float d_x = adx / h_w * 100.0f;
    const float d_y = ady / h_h * 100.0f;
    const float d_xy = sqrtf(dxc * dxc + dyc * dyc) / (h_w + h_h) * 100.0f;
    const float dx_ratio = adx / im_w * 100.0f;
    const float dy_ratio = ady / im_h * 100.0f;
    const float det_y = (ady > 1e-5f) ? dyc : ((dyc > 0.0f) ? 1e-5f : -1e-5f);
    const float angle = atanf(dxc / det_y);
    const float area_scale = (o_w * o_h) / (h_w * h_h);
    const float o_scale = o_h / o_w;

    const float ix1 = fmaxf(hx1, ox1), iy1 = fmaxf(hy1, oy1);
    const float ix2 = fminf(hx2, ox2), iy2 = fminf(hy2, oy2);
    const float inter = fmaxf(ix2 - ix1, 0.0f) * fmaxf(iy2 - iy1, 0.0f);
    const float uni = h_w * h_h + o_w * o_h - inter;
    const float iou = (inter > 0.0f) ? inter / uni : 0.0f;

    float* g = geo + (size_t)p * 9;
    g[0] = d_x; g[1] = d_y; g[2] = d_xy;
    g[3] = dx_ratio; g[4] = dy_ratio; g[5] = angle;
    g[6] = area_scale; g[7] = o_scale; g[8] = iou;

    const float ux1 = fminf(ox1, hx1), uy1 = fminf(oy1, hy1);
    const float ux2 = fmaxf(ox2, hx2), uy2 = fmaxf(oy2, hy2);
    ho_ratio[p] = (ux2 - ux1) * (uy2 - uy1) / im_area * 100.0f;

    if (p < 64) {
        const float* hb2 = HBox + p * 6;
        h_ratio[p] = (hb2[2] - hb2[0]) * (hb2[3] - hb2[1]) / im_area * 100.0f;
        const float* ob2 = OBox + p * 6;
        o_ratio[p] = (ob2[2] - ob2[0]) * (ob2[3] - ob2[1]) / im_area * 100.0f;
    }
}

extern "C" void kernel_launch(void* const* d_in, const int* in_sizes, int n_in,
                              void* d_out, int out_size, void* d_ws, size_t ws_size,
                              hipStream_t stream) {
    const float* feat = (const float*)d_in[0];
    const float* HBox = (const float*)d_in[1];
    const float* OBox = (const float*)d_in[2];
    const int* im_h = (const int*)d_in[3];
    const int* im_w = (const int*)d_in[4];
    float* out = (float*)d_out;

    // 32 channel-groups x 72 roi-groups (16 rois each, same batch b)
    dim3 grid(32, 72);
    roi_align_kernel<<<grid, 256, 0, stream>>>(feat, HBox, OBox, im_h, im_w, out);

    geom_kernel<<<4, 256, 0, stream>>>(HBox, OBox, im_h, im_w,
                                       out + OFF_G, out + OFF_HR,
                                       out + OFF_OR, out + OFF_UR);
}

// Round 2
// 239.115 us; speedup vs baseline: 1.0222x; 1.0222x over previous
//
#include <hip/hip_runtime.h>

// features: (B=4, C=1024, 14, 14) fp32; H_Box/O_Box: (4,16,6); im_h=480, im_w=640
// Outputs (flat concat, fp32):
//   H_Node   (4,16,1024,7,7)      = 3,211,264   @ 0
//   O_Node   (4,16,1024,7,7)      = 3,211,264   @ 3,211,264
//   H_O_Node (4,16,16,1024,7,7)   = 51,380,224  @ 6,422,528
//   geometry (4,16,16,9)          = 9,216       @ 57,802,752
//   h_ratio  (4,16)               = 64          @ 57,811,968
//   o_ratio  (4,16)               = 64          @ 57,812,032
//   ho_ratio (4,16,16)            = 1,024       @ 57,812,096

#define C_CH   1024
#define HW     14
#define PLANE  196              // 14*14 floats per channel plane
#define OUTS   7
#define TILE   (C_CH * OUTS * OUTS)   // 50176 elems per roi
#define OFF_O  3211264
#define OFF_U  6422528
#define OFF_G  57802752
#define OFF_HR 57811968
#define OFF_OR 57812032
#define OFF_UR 57812096

// Occupancy-first config: 16 channels staged per block -> 13,312 B LDS ->
// residency is THREAD-capped at 8 blocks/CU = 32 waves/CU (hardware max),
// up from 5 blocks (20 waves) at the old 32-channel tile. The roi loop is a
// latency chain (descriptor -> ds_read -> fma -> store); more waves/SIMD is
// the lever that hides it. __launch_bounds__(256,8) pins VGPR <= 64 so the
// 32-wave ceiling is reachable.
#define CH_PER_BLK   16
#define ROI_PER_BLK  16         // rois sharing one staging (288 % 16 == 0 -> same b)
#define CH_PER_WAVE  4          // 4 waves x 4 = 16

#define BXS    (CH_PER_BLK * PLANE)      // 3136 dwords: staged box slice base

// grid = (64 channel-groups, 72 roi-groups + 1 geom row), block = 256.
// Stage 16 planes -> LDS (coalesced float4; 196 = 49*4 so float4s never
// straddle planes). Lane = output position (49 active of 64); wave owns 4
// channels; block loops 16 rois over the staged planes.
// Per channel: taps at dword offsets {0,1,14,15} from a per-channel base ->
// compiler merges into 2x ds_read2_b32; stores use immediate offsets op[49*k].
__global__ __launch_bounds__(256, 8) void roi_align_kernel(
    const float* __restrict__ feat,
    const float* __restrict__ HBox,
    const float* __restrict__ OBox,
    const int* __restrict__ im_h_p,
    const int* __restrict__ im_w_p,
    float* __restrict__ out)
{
    __shared__ float lds[BXS + 192];     // 3328 floats = 13,312 B

    const float im_w = (float)(*im_w_p);
    const float im_h = (float)(*im_h_p);

    // ---- merged pairwise-geometry row (4 active blocks, rest retire) ----
    if (blockIdx.y == 72) {
        if (blockIdx.x >= 4) return;
        const int p = blockIdx.x * 256 + threadIdx.x;   // 0..1023
        const float im_area = im_h * im_w;

        const int b = p >> 8;
        const int h = (p >> 4) & 15;
        const int o = p & 15;
        const float* hb = HBox + (b * 16 + h) * 6;
        const float* ob = OBox + (b * 16 + o) * 6;
        const float hx1 = hb[0], hy1 = hb[1], hx2 = hb[2], hy2 = hb[3];
        const float ox1 = ob[0], oy1 = ob[1], ox2 = ob[2], oy2 = ob[3];

        const float h_cx = (hx1 + hx2) * 0.5f, h_cy = (hy1 + hy2) * 0.5f;
        const float h_w = hx2 - hx1, h_h = hy2 - hy1;
        const float o_cx = (ox1 + ox2) * 0.5f, o_cy = (oy1 + oy2) * 0.5f;
        const float o_w = ox2 - ox1, o_h = oy2 - oy1;

        const float dxc = h_cx - o_cx;
        const float dyc = h_cy - o_cy;
        const float adx = fabsf(dxc), ady = fabsf(dyc);

        const float d_x = adx / h_w * 100.0f;
        const float d_y = ady / h_h * 100.0f;
        const float d_xy = sqrtf(dxc * dxc + dyc * dyc) / (h_w + h_h) * 100.0f;
        const float dx_ratio = adx / im_w * 100.0f;
        const float dy_ratio = ady / im_h * 100.0f;
        const float det_y = (ady > 1e-5f) ? dyc : ((dyc > 0.0f) ? 1e-5f : -1e-5f);
        const float angle = atanf(dxc / det_y);
        const float area_scale = (o_w * o_h) / (h_w * h_h);
        const float o_scale = o_h / o_w;

        const float ix1 = fmaxf(hx1, ox1), iy1 = fmaxf(hy1, oy1);
        const float ix2 = fminf(hx2, ox2), iy2 = fminf(hy2, oy2);
        const float inter = fmaxf(ix2 - ix1, 0.0f) * fmaxf(iy2 - iy1, 0.0f);
        const float uni = h_w * h_h + o_w * o_h - inter;
        const float iou = (inter > 0.0f) ? inter / uni : 0.0f;

        float* g = out + OFF_G + (size_t)p * 9;
        g[0] = d_x; g[1] = d_y; g[2] = d_xy;
        g[3] = dx_ratio; g[4] = dy_ratio; g[5] = angle;
        g[6] = area_scale; g[7] = o_scale; g[8] = iou;

        const float ux1 = fminf(ox1, hx1), uy1 = fminf(oy1, hy1);
        const float ux2 = fmaxf(ox2, hx2), uy2 = fmaxf(oy2, hy2);
        out[OFF_UR + p] = (ux2 - ux1) * (uy2 - uy1) / im_area * 100.0f;

        if (p < 64) {
            const float* hb2 = HBox + p * 6;
            out[OFF_HR + p] = (hb2[2] - hb2[0]) * (hb2[3] - hb2[1]) / im_area * 100.0f;
            const float* ob2 = OBox + p * 6;
            out[OFF_OR + p] = (ob2[2] - ob2[0]) * (ob2[3] - ob2[1]) / im_area * 100.0f;
        }
        return;
    }

    const int c0 = blockIdx.x * CH_PER_BLK;
    const int g0 = blockIdx.y * ROI_PER_BLK;
    const int b  = g0 / 288;                    // block-uniform

    // ---- stage 16 contiguous planes, fully coalesced ----
    {
        const float4* g4 = (const float4*)(feat + ((size_t)b * C_CH + c0) * PLANE);
        float4* l4 = (float4*)lds;
        for (int i = threadIdx.x; i < (CH_PER_BLK * PLANE / 4); i += 256)
            l4[i] = g4[i];
    }
    // ---- stage this batch's box slices (16x6 H + 16x6 O = 192 floats) ----
    if (threadIdx.x < 96)
        lds[BXS + threadIdx.x] = HBox[b * 96 + threadIdx.x];
    else if (threadIdx.x < 192)
        lds[BXS + threadIdx.x] = OBox[b * 96 + (threadIdx.x - 96)];
    __syncthreads();

    const int lane = threadIdx.x & 63;
    const int wave = threadIdx.x >> 6;
    if (lane >= 49) return;                     // no further block-wide syncs

    const int pos = lane;
    const int oy = pos / 7;
    const int ox = pos - oy * 7;

    const float scx = (224.0f / im_w) * (1.0f / 16.0f);
    const float scy = (224.0f / im_h) * (1.0f / 16.0f);

    const float* ldw = lds + (wave * CH_PER_WAVE) * PLANE;
    const int cw = c0 + wave * CH_PER_WAVE;     // first channel this wave owns

    const float* hbx = lds + BXS;               // staged H boxes (16x6)
    const float* obx = lds + BXS + 96;          // staged O boxes (16x6)

    for (int ri = 0; ri < ROI_PER_BLK; ++ri) {
        const int g = g0 + ri;
        const int j = g - b * 288;              // block-uniform branch below

        float x1, y1, x2, y2;
        size_t outBase;
        if (j < 16) {
            const float* bx = hbx + j * 6;
            x1 = bx[0]; y1 = bx[1]; x2 = bx[2]; y2 = bx[3];
            outBase = (size_t)(b * 16 + j) * TILE;
        } else if (j < 32) {
            const float* bx = obx + (j - 16) * 6;
            x1 = bx[0]; y1 = bx[1]; x2 = bx[2]; y2 = bx[3];
            outBase = OFF_O + (size_t)(b * 16 + (j - 16)) * TILE;
        } else {
            const int u = j - 32;
            const float* hb = hbx + (u >> 4) * 6;
            const float* ob = obx + (u & 15) * 6;
            x1 = fminf(ob[0], hb[0]);
            y1 = fminf(ob[1], hb[1]);
            x2 = fmaxf(ob[2], hb[2]);
            y2 = fmaxf(ob[3], hb[3]);
            outBase = OFF_U + (size_t)(b * 256 + u) * TILE;
        }

        // bilinear descriptor (once per roi, loop-invariant registers)
        const float bx1 = x1 * scx;
        const float by1 = y1 * scy;
        const float bw = (x2 * scx - bx1) * (1.0f / OUTS);
        const float bh = (y2 * scy - by1) * (1.0f / OUTS);
        float X = bx1 + ((float)ox + 0.5f) * bw;
        float Y = by1 + ((float)oy + 0.5f) * bh;
        X = fminf(fmaxf(X, 0.0f), (float)(HW - 1));
        Y = fminf(fmaxf(Y, 0.0f), (float)(HW - 1));
        // clamp base to <=12 so x1i=x0+1 always; X==13 -> lx=1 -> weight flows
        // to f01 which equals reference's clamped f00. Bit-equivalent result.
        const int x0 = min((int)floorf(X), HW - 2);
        const int y0 = min((int)floorf(Y), HW - 2);
        const float lx = X - (float)x0;
        const float ly = Y - (float)y0;
        const float w00 = (1.0f - ly) * (1.0f - lx);
        const float w01 = (1.0f - ly) * lx;
        const float w10 = ly * (1.0f - lx);
        const float w11 = ly * lx;
        const int off = y0 * HW + x0;

        const float* lp = ldw + off;
        float* op = out + outBase + (size_t)cw * 49 + pos;
#pragma unroll
        for (int k = 0; k < CH_PER_WAVE; ++k) {
            // dword offsets {0,1,14,15} from per-channel base -> 2x ds_read2_b32
            const float f00 = lp[0];
            const float f01 = lp[1];
            const float f10 = lp[HW];
            const float f11 = lp[HW + 1];
            op[49 * k] = f00 * w00 + f01 * w01 + f10 * w10 + f11 * w11;
            lp += PLANE;
        }
    }
}

extern "C" void kernel_launch(void* const* d_in, const int* in_sizes, int n_in,
                              void* d_out, int out_size, void* d_ws, size_t ws_size,
                              hipStream_t stream) {
    const float* feat = (const float*)d_in[0];
    const float* HBox = (const float*)d_in[1];
    const float* OBox = (const float*)d_in[2];
    const int* im_h = (const int*)d_in[3];
    const int* im_w = (const int*)d_in[4];
    float* out = (float*)d_out;

    // 64 channel-groups x (72 roi-groups + 1 geometry row)
    dim3 grid(64, 73);
    roi_align_kernel<<<grid, 256, 0, stream>>>(feat, HBox, OBox, im_h, im_w, out);
}